// Round 12
// baseline (650.002 us; speedup 1.0000x reference)
//
#include <hip/hip_runtime.h>
#include <hip/hip_bf16.h>

// out[b,s,e] = sum_d x[b,s,d] * kv[d,e],  kv[d,e] = sum_m keys[m,d]*vals[m,e]
// B*S = 8192, D = 1024, M = 65536. fp32 in/out; internal bf16 MFMA.
//
// Fast path (needs 22 MB ws):
//   1. kv_gemm_fused: 8-phase 256x256 GEMM that stages RAW fp32 keys/vals
//      (reg-staged transpose+convert, T14 split: loads @p0, vmcnt+ds_write
//      @p3), split-K 16, fp32 atomic reduce into kvw[e][d].  No separate
//      convert pass, no bf16 operand images in HBM.
//   2. convert_rows: fp32 row-major -> 16KB tile format (x and kvw).
//   3. out_gemm8: 8-phase 128x256 GEMM, plain stores.

typedef __attribute__((ext_vector_type(8))) __bf16 bf16x8;
typedef __attribute__((ext_vector_type(4))) __bf16 bf16x4;
typedef __attribute__((ext_vector_type(4))) float  f32x4;

#define D_DIM   1024
#define M_DIM   65536
#define ROWS    8192
#define NCHUNK  16
#define MC      (M_DIM / NCHUNK)
#define BT      128
#define BK      64
#define LDK     72
#define TILE_BYTES 16384           // one [128 rows][64 k] bf16 tile

__device__ __forceinline__ f32x4 mfma16(bf16x8 a, bf16x8 b, f32x4 c) {
    return __builtin_amdgcn_mfma_f32_16x16x32_bf16(a, b, c, 0, 0, 0);
}

__device__ __forceinline__ void gl_lds16(const void* gsrc, void* ldst) {
    __builtin_amdgcn_global_load_lds(
        (const __attribute__((address_space(1))) unsigned int*)gsrc,
        (__attribute__((address_space(3))) unsigned int*)ldst,
        16, 0, 0);
}

// ---------------------------------------------------------------------------
// Kernel B-fused: kvw[e][d] += sum_m vals[m][e] * keys[m][d], raw fp32 in.
// 8-phase 256x256, 512 thr / 8 waves.  Staging: waves 0-3 stage the V-panel
// (vals rows -> e-row tiles), waves 4-7 the K-panel.  Per K-tile (64 m):
// 16 f32x4 loads issued @p0 (900cy in flight), @p3 vmcnt(0) -> in-reg 4x4
// transpose+cvt -> swizzled ds_write_b64 into buf^1 -> lgkmcnt(0) -> barrier.
// LDS tile format identical to the gl_lds version (cl ^ (row&7) swizzle).
// ---------------------------------------------------------------------------
__global__ __launch_bounds__(512, 1)
void kv_gemm_fused(const float* __restrict__ keys,
                   const float* __restrict__ vals,
                   float* __restrict__ kvw)
{
    // [slot][subtile: 0=V-lo 1=V-hi 2=K-lo 3=K-hi][16KB]
    __shared__ __align__(16) char lds[2][4][TILE_BYTES];

    const int tid  = threadIdx.x;
    const int lane = tid & 63;
    const int wave = tid >> 6;        // 0..7
    const int we   = wave >> 2;       // 0..1  e-half (A)
    const int wd   = wave & 3;        // 0..3  d-dim (B)

    // XCD-bijective: xcd = bx&7 owns 2 chunks x 16 tiles (panel sharers co-L2)
    const int bx    = blockIdx.x;
    const int xcd   = bx & 7;
    const int idx   = bx >> 3;                 // 0..31
    const int chunk = ((idx >> 4) << 3) | xcd; // 0..15
    const int t16   = idx & 15;
    const int E8    = t16 >> 2;                // 0..3
    const int D8    = t16 & 3;                 // 0..3

    const size_t mbase = (size_t)chunk * MC;   // 4096 m per chunk = 64 K-tiles

    // ---- staging role: 256-thread groups, R10 transpose mapping ----
    const int grp = tid >> 8;             // 0 = V(vals, e-cols), 1 = K(keys, d-cols)
    const int tq  = tid & 255;
    const int q   = tq & 15;              // m-quad
    const int dcb = tq >> 4;              // 0..15
    const int clq  = q >> 1;              // logical chunk
    const int half = (q & 1) << 3;        // byte half of granule pair
    const float* psrc = grp ? keys : vals;
    const int c0 = (grp ? D8 : E8) * 256;

    const int l15 = lane & 15;
    const int l7  = lane & 7;
    const int hi  = lane >> 4;

    f32x4 acc[8][4] = {};
    f32x4 v[4][4];

    auto stage_load = [&](int t) {
        #pragma unroll
        for (int i = 0; i < 4; ++i) {
            const int cq = dcb + 16 * i;              // col-quad 0..63
            #pragma unroll
            for (int r = 0; r < 4; ++r)
                v[i][r] = *(const f32x4*)(psrc
                    + (mbase + (size_t)t * BK + 4 * q + r) * D_DIM + c0 + 4 * cq);
        }
    };
    auto stage_write = [&](int buf) {
        #pragma unroll
        for (int i = 0; i < 4; ++i) {
            const int cq = dcb + 16 * i;
            #pragma unroll
            for (int j = 0; j < 4; ++j) {
                bf16x4 w;
                #pragma unroll
                for (int r = 0; r < 4; ++r) w[r] = (__bf16)v[i][r][j];
                const int row = 4 * cq + j;           // 0..255 (e or d local)
                const int sub = 2 * grp + (row >> 7);
                const int dl  = row & 127;
                *(bf16x4*)(&lds[buf][sub][0] + dl * 128
                           + ((clq ^ (dl & 7)) << 4) + half) = w;
            }
        }
    };

    // ---- prologue: tile 0 ----
    stage_load(0);
    asm volatile("s_waitcnt vmcnt(0)" ::: "memory");
    stage_write(0);
    asm volatile("s_waitcnt lgkmcnt(0)" ::: "memory");
    __builtin_amdgcn_s_barrier();

    bf16x8 bfr[4][2];

    for (int t = 0; t < 64; ++t) {
        const int buf = t & 1;
        const char* abase = &lds[buf][we][0];
        const char* bbase = &lds[buf][2 + (wd >> 1)][0];
        const int brow0 = (wd & 1) * 64;

        #pragma unroll
        for (int p = 0; p < 4; ++p) {
            // ---- ds_read this phase's A frags ----
            bf16x8 afr[2][2];
            #pragma unroll
            for (int j = 0; j < 2; ++j)
                #pragma unroll
                for (int ks = 0; ks < 2; ++ks) {
                    const int row = (2 * p + j) * 16 + l15;
                    afr[j][ks] = *(const bf16x8*)(abase + row * 128
                                   + (((ks << 2) + hi) ^ l7) * 16);
                }
            if (p == 0) {
                #pragma unroll
                for (int n = 0; n < 4; ++n)
                    #pragma unroll
                    for (int ks = 0; ks < 2; ++ks) {
                        const int row = brow0 + n * 16 + l15;
                        bfr[n][ks] = *(const bf16x8*)(bbase + row * 128
                                       + (((ks << 2) + hi) ^ l7) * 16);
                    }
                if (t + 1 < 64) stage_load(t + 1);   // 16 loads, 3 phases in flight
            }
            __builtin_amdgcn_s_barrier();
            asm volatile("s_waitcnt lgkmcnt(0)" ::: "memory");
            __builtin_amdgcn_sched_barrier(0);
            __builtin_amdgcn_s_setprio(1);
            #pragma unroll
            for (int j = 0; j < 2; ++j)
                #pragma unroll
                for (int n = 0; n < 4; ++n)
                    #pragma unroll
                    for (int ks = 0; ks < 2; ++ks)
                        acc[2 * p + j][n] = mfma16(afr[j][ks], bfr[n][ks],
                                                   acc[2 * p + j][n]);
            __builtin_amdgcn_s_setprio(0);
            if (p == 3 && t + 1 < 64) {
                asm volatile("s_waitcnt vmcnt(0)" ::: "memory");   // loads landed
                stage_write(buf ^ 1);                               // cvt + ds_write
                asm volatile("s_waitcnt lgkmcnt(0)" ::: "memory"); // writes visible
            }
            __builtin_amdgcn_s_barrier();
        }
    }

    // ---- epilogue: C row = V rows = e; col = K rows = d  (m89 map) ----
    const int rb = hi * 4;
    #pragma unroll
    for (int mi = 0; mi < 8; ++mi) {
        #pragma unroll
        for (int ni = 0; ni < 4; ++ni) {
            const int d = D8 * 256 + wd * 64 + ni * 16 + l15;
            #pragma unroll
            for (int r = 0; r < 4; ++r) {
                const int e = E8 * 256 + we * 128 + mi * 16 + rb + r;
                atomicAdd(kvw + (size_t)e * D_DIM + d, acc[mi][ni][r]);
            }
        }
    }
}

// ---------------------------------------------------------------------------
// Kernel A2: fp32 row-major [R][1024] -> tiles [r_tile][16][128][64], NO
// transpose.  Register-only, fully coalesced.  grid = (R/128, 16).
// ---------------------------------------------------------------------------
__global__ __launch_bounds__(256)
void convert_rows(const float* __restrict__ src,
                  __hip_bfloat16* __restrict__ dstT)
{
    const int tid = threadIdx.x;
    const int rt  = blockIdx.x;
    const int t   = blockIdx.y;
    const int r0  = rt * 128, d0 = t * 64;
    char* tile = (char*)dstT + ((size_t)rt * 16 + t) * TILE_BYTES;
    #pragma unroll
    for (int it = 0; it < 4; ++it) {
        const int idx = tid + it * 256;     // 0..1023
        const int r   = idx >> 3;           // 0..127
        const int cl  = idx & 7;            // logical chunk
        const float* p = src + (size_t)(r0 + r) * D_DIM + d0 + cl * 8;
        f32x4 a = *(const f32x4*)p;
        f32x4 b = *(const f32x4*)(p + 4);
        bf16x8 w;
        w[0] = (__bf16)a[0]; w[1] = (__bf16)a[1]; w[2] = (__bf16)a[2]; w[3] = (__bf16)a[3];
        w[4] = (__bf16)b[0]; w[5] = (__bf16)b[1]; w[6] = (__bf16)b[2]; w[7] = (__bf16)b[3];
        *(bf16x8*)(tile + r * 128 + ((cl ^ (r & 7)) * 16)) = w;
    }
}

// ---------------------------------------------------------------------------
// Kernel C: out[r][e] = sum_d x[r][d] * kvw[e][d], both in tile format.
// 8-phase clone, 128(r) x 256(e) tile (unchanged from R9-R11).
// ---------------------------------------------------------------------------
__global__ __launch_bounds__(512, 1)
void out_gemm8(const __hip_bfloat16* __restrict__ xbT,
               const __hip_bfloat16* __restrict__ kvbT,
               float* __restrict__ out)
{
    __shared__ __align__(16) char lds[2][3][TILE_BYTES];   // 96 KB

    const int tid  = threadIdx.x;
    const int lane = tid & 63;
    const int wave = tid >> 6;
    const int wr   = wave >> 2;       // 0..1 r-half
    const int wee  = wave & 3;        // 0..3 e-quarter

    const int bx = blockIdx.x;
    const int rt = bx & 63;           // r-tile (128 rows)
    const int be = bx >> 6;           // 0..3 (256-col e-tile)

    const int l15 = lane & 15;
    const int l7  = lane & 7;
    const int hi  = lane >> 4;

    f32x4 acc[4][4] = {};

    const char* Xb = (const char*)xbT;
    const char* Kv = (const char*)kvbT;

    auto tileA = [&](int t) -> const char* {
        return Xb + ((size_t)rt * 16 + t) * TILE_BYTES;
    };
    auto tileB = [&](int j, int t) -> const char* {
        return Kv + ((size_t)(2 * be + j) * 16 + t) * TILE_BYTES;
    };
    auto stage_sub = [&](int buf, int sub, const char* tile) {
        char* dst = &lds[buf][sub][wave * 1024];
        const char* s = tile + wave * 1024 + lane * 16;
        gl_lds16(s,        dst);
        gl_lds16(s + 8192, dst + 8192);
    };

    stage_sub(0, 0, tileA(0));
    stage_sub(0, 1, tileB(0, 0));
    stage_sub(0, 2, tileB(1, 0));
    asm volatile("s_waitcnt vmcnt(0)" ::: "memory");
    __builtin_amdgcn_s_barrier();

    bf16x8 bfr[4][2];

    for (int t = 0; t < 16; ++t) {
        const int buf = t & 1;
        const char* abase = &lds[buf][0][0];
        const char* bbase = &lds[buf][1 + (wee >> 1)][0];
        const int brow0 = (wee & 1) * 64;

        #pragma unroll
        for (int p = 0; p < 4; ++p) {
            bf16x8 afr[2];
            #pragma unroll
            for (int ks = 0; ks < 2; ++ks) {
                const int row = wr * 64 + p * 16 + l15;
                afr[ks] = *(const bf16x8*)(abase + row * 128
                              + (((ks << 2) + hi) ^ l7) * 16);
            }
            if (p == 0) {
                #pragma unroll
                for (int n = 0; n < 4; ++n)
                    #pragma unroll
                    for (int ks = 0; ks < 2; ++ks) {
                        const int row = brow0 + n * 16 + l15;
                        bfr[n][ks] = *(const bf16x8*)(bbase + row * 128
                                       + (((ks << 2) + hi) ^ l7) * 16);
                    }
            }
            if (p == 0 && t + 1 < 16) stage_sub(buf ^ 1, 0, tileA(t + 1));
            if (p == 1 && t + 1 < 16) {
                stage_sub(buf ^ 1, 1, tileB(0, t + 1));
                stage_sub(buf ^ 1, 2, tileB(1, t + 1));
            }
            __builtin_amdgcn_s_barrier();
            asm volatile("s_waitcnt lgkmcnt(0)" ::: "memory");
            __builtin_amdgcn_sched_barrier(0);
            __builtin_amdgcn_s_setprio(1);
            #pragma unroll
            for (int n = 0; n < 4; ++n)
                #pragma unroll
                for (int ks = 0; ks < 2; ++ks)
                    acc[p][n] = mfma16(afr[ks], bfr[n][ks], acc[p][n]);
            __builtin_amdgcn_s_setprio(0);
            if (p == 3)
                asm volatile("s_waitcnt vmcnt(0)" ::: "memory");
            __builtin_amdgcn_s_barrier();
        }
    }

    // epilogue: C row = x rows = r; col = kvb rows = e  (m89 map)
    const int r0 = rt * 128, e0 = be * 256;
    #pragma unroll
    for (int mi = 0; mi < 4; ++mi) {
        #pragma unroll
        for (int ni = 0; ni < 4; ++ni) {
            const int e = e0 + wee * 64 + ni * 16 + l15;
            #pragma unroll
            for (int r = 0; r < 4; ++r) {
                const int rr = r0 + wr * 64 + mi * 16 + hi * 4 + r;
                out[(size_t)rr * D_DIM + e] = acc[mi][ni][r];
            }
        }
    }
}

// ---------------------------------------------------------------------------
// Fallbacks (ws too small): R1 fused kv path + old out path, known-correct.
// ---------------------------------------------------------------------------
__global__ __launch_bounds__(256)
void kv_partial_kernel(const float* __restrict__ keys,
                       const float* __restrict__ vals,
                       float* __restrict__ kvw)
{
    __shared__ __bf16 Ktl[BT][LDK];
    __shared__ __bf16 Vtl[BT][LDK];

    const int tid  = threadIdx.x;
    const int lane = tid & 63;
    const int wave = tid >> 6;
    const int wr   = wave >> 1;
    const int wc   = wave & 1;

    const int tile  = blockIdx.x & 63;
    const int chunk = blockIdx.x >> 6;
    const int d0 = (tile >> 3) * BT;
    const int e0 = (tile & 7) * BT;
    const size_t mbeg = (size_t)chunk * MC;

    f32x4 acc[4][4] = {};
    const int kg  = tid & 15;
    const int d4a = tid >> 4;

    for (int ms = 0; ms < MC; ms += BK) {
        #pragma unroll
        for (int i = 0; i < 2; ++i) {
            const int dloc = (d4a + i * 16) * 4;
            const size_t mrow = mbeg + ms + (size_t)kg * 4;
            f32x4 kr[4], vr[4];
            #pragma unroll
            for (int r = 0; r < 4; ++r) {
                kr[r] = *(const f32x4*)(keys + (mrow + r) * D_DIM + d0 + dloc);
                vr[r] = *(const f32x4*)(vals + (mrow + r) * D_DIM + e0 + dloc);
            }
            #pragma unroll
            for (int j = 0; j < 4; ++j) {
                bf16x4 wk, wv;
                #pragma unroll
                for (int r = 0; r < 4; ++r) {
                    wk[r] = (__bf16)kr[r][j];
                    wv[r] = (__bf16)vr[r][j];
                }
                *(bf16x4*)&Ktl[dloc + j][kg * 4] = wk;
                *(bf16x4*)&Vtl[dloc + j][kg * 4] = wv;
            }
        }
        __syncthreads();

        #pragma unroll
        for (int ks = 0; ks < BK; ks += 32) {
            bf16x8 af[4], bf[4];
            #pragma unroll
            for (int t = 0; t < 4; ++t) {
                af[t] = *(const bf16x8*)&Ktl[wr * 64 + t * 16 + (lane & 15)][ks + (lane >> 4) * 8];
                bf[t] = *(const bf16x8*)&Vtl[wc * 64 + t * 16 + (lane & 15)][ks + (lane >> 4) * 8];
            }
            #pragma unroll
            for (int mi = 0; mi < 4; ++mi)
                #pragma unroll
                for (int ni = 0; ni < 4; ++ni)
                    acc[mi][ni] = mfma16(af[mi], bf[ni], acc[mi][ni]);
        }
        __syncthreads();
    }

    const int rbase = (lane >> 4) * 4;
    const int cidx  = lane & 15;
    #pragma unroll
    for (int mi = 0; mi < 4; ++mi) {
        #pragma unroll
        for (int ni = 0; ni < 4; ++ni) {
            const int e = e0 + wc * 64 + ni * 16 + cidx;
            #pragma unroll
            for (int reg = 0; reg < 4; ++reg) {
                const int d = d0 + wr * 64 + mi * 16 + rbase + reg;
                atomicAdd(kvw + (size_t)e * D_DIM + d, acc[mi][ni][reg]);
            }
        }
    }
}

__global__ __launch_bounds__(256)
void out_gemm_kernel(const float* __restrict__ x,
                     const float* __restrict__ kvw,
                     float* __restrict__ out)
{
    __shared__ __bf16 Xt[BT][LDK];
    __shared__ __bf16 Wt[BT][LDK];

    const int tid  = threadIdx.x;
    const int lane = tid & 63;
    const int wave = tid >> 6;
    const int wr   = wave >> 1;
    const int wc   = wave & 1;

    const int r0 = blockIdx.x * BT;
    const int e0 = blockIdx.y * BT;

    f32x4 acc[4][4] = {};

    for (int ks0 = 0; ks0 < D_DIM; ks0 += BK) {
        #pragma unroll
        for (int i = 0; i < 8; ++i) {
            const int idx = tid + i * 256;
            const int row = idx >> 4;
            const int col = (idx & 15) * 4;
            f32x4 xa = *(const f32x4*)(x   + (size_t)(r0 + row) * D_DIM + ks0 + col);
            f32x4 wa = *(const f32x4*)(kvw + (size_t)(e0 + row) * D_DIM + ks0 + col);
            bf16x4 xb, wb;
            #pragma unroll
            for (int j = 0; j < 4; ++j) {
                xb[j] = (__bf16)xa[j];
                wb[j] = (__bf16)wa[j];
            }
            *(bf16x4*)&Xt[row][col] = xb;
            *(bf16x4*)&Wt[row][col] = wb;
        }
        __syncthreads();

        #pragma unroll
        for (int ks = 0; ks < BK; ks += 32) {
            bf16x8 af[4], bf[4];
            #pragma unroll
            for (int t = 0; t < 4; ++t) {
                af[t] = *(const bf16x8*)&Xt[wr * 64 + t * 16 + (lane & 15)][ks + (lane >> 4) * 8];
                bf[t] = *(const bf16x8*)&Wt[wc * 64 + t * 16 + (lane & 15)][ks + (lane >> 4) * 8];
            }
            #pragma unroll
            for (int mi = 0; mi < 4; ++mi)
                #pragma unroll
                for (int ni = 0; ni < 4; ++ni)
                    acc[mi][ni] = mfma16(af[mi], bf[ni], acc[mi][ni]);
        }
        __syncthreads();
    }

    const int rbase = (lane >> 4) * 4;
    const int cidx  = lane & 15;
    #pragma unroll
    for (int mi = 0; mi < 4; ++mi) {
        #pragma unroll
        for (int ni = 0; ni < 4; ++ni) {
            const int e = e0 + wc * 64 + ni * 16 + cidx;
            #pragma unroll
            for (int reg = 0; reg < 4; ++reg) {
                const int r = r0 + wr * 64 + mi * 16 + rbase + reg;
                out[(size_t)r * D_DIM + e] = acc[mi][ni][reg];
            }
        }
    }
}

extern "C" void kernel_launch(void* const* d_in, const int* in_sizes, int n_in,
                              void* d_out, int out_size, void* d_ws, size_t ws_size,
                              hipStream_t stream) {
    const float* x    = (const float*)d_in[0];
    const float* keys = (const float*)d_in[2];
    const float* vals = (const float*)d_in[3];
    float* out = (float*)d_out;

    const size_t kvw_bytes = (size_t)D_DIM * D_DIM * sizeof(float);          // 4 MiB
    const size_t xb_bytes  = (size_t)ROWS * D_DIM * sizeof(__hip_bfloat16);  // 16 MiB
    const size_t kvb_bytes = (size_t)D_DIM * D_DIM * sizeof(__hip_bfloat16); // 2 MiB
    const size_t need_fused = kvw_bytes + xb_bytes + kvb_bytes;              // 22 MiB

    float* kvw = (float*)d_ws;
    hipMemsetAsync(kvw, 0, kvw_bytes, stream);

    if (ws_size >= need_fused) {
        __hip_bfloat16* xbT  = (__hip_bfloat16*)((char*)d_ws + kvw_bytes);
        __hip_bfloat16* kvbT = (__hip_bfloat16*)((char*)d_ws + kvw_bytes + xb_bytes);
        kv_gemm_fused<<<dim3(256), dim3(512), 0, stream>>>(keys, vals, kvw);
        convert_rows<<<dim3(ROWS / 128, 16), dim3(256), 0, stream>>>(x, xbT);
        convert_rows<<<dim3(D_DIM / 128, 16), dim3(256), 0, stream>>>(kvw, kvbT);
        out_gemm8<<<dim3(256), dim3(512), 0, stream>>>(xbT, kvbT, out);
    } else {
        kv_partial_kernel<<<dim3(64 * NCHUNK), dim3(256), 0, stream>>>(keys, vals, kvw);
        out_gemm_kernel<<<dim3(64, 8), dim3(256), 0, stream>>>(x, kvw, out);
    }
}

// Round 13
// 351.887 us; speedup vs baseline: 1.8472x; 1.8472x over previous
//
#include <hip/hip_runtime.h>
#include <hip/hip_bf16.h>

// out[b,s,e] = sum_d x[b,s,d] * kv[d,e],  kv[d,e] = sum_m keys[m,d]*vals[m,e]
// B*S = 8192, D = 1024, M = 65536. fp32 in/out; internal bf16 MFMA.
//
// Fast path (needs 278 MB ws) — best-of-each composition:
//   1. convert_tile (R8 variant, best measured: 183us): fp32 [M][D] -> bf16
//      16KB tiles [row_tile][m_step][128][64], chunk-swizzle cl=c^(row&7)
//      baked in.  Full-row streaming, 128KB LDS, granule swizzle.
//   2. kv_gemm8 (R6, ~110us): 8-phase 256x256 (T3+T4+T5), split-K 16,
//      atomics into kvw.
//   3. convert_rows (~10us): fp32 row-major -> tile format (x and kvw).
//   4. out_gemm8 (R9, ~25us): 8-phase 128x256, plain stores.

typedef __attribute__((ext_vector_type(8))) __bf16 bf16x8;
typedef __attribute__((ext_vector_type(4))) __bf16 bf16x4;
typedef __attribute__((ext_vector_type(4))) float  f32x4;

#define D_DIM   1024
#define M_DIM   65536
#define ROWS    8192
#define NCHUNK  16
#define MC      (M_DIM / NCHUNK)
#define BT      128
#define BK      64
#define LDK     72
#define TILE_BYTES 16384           // one [128 rows][64 k] bf16 tile

__device__ __forceinline__ f32x4 mfma16(bf16x8 a, bf16x8 b, f32x4 c) {
    return __builtin_amdgcn_mfma_f32_16x16x32_bf16(a, b, c, 0, 0, 0);
}

__device__ __forceinline__ void gl_lds16(const void* gsrc, void* ldst) {
    __builtin_amdgcn_global_load_lds(
        (const __attribute__((address_space(1))) unsigned int*)gsrc,
        (__attribute__((address_space(3))) unsigned int*)ldst,
        16, 0, 0);
}

// ---------------------------------------------------------------------------
// Kernel A (R8 variant): fp32 [M][D] -> swizzled bf16 tiles.  Full-row
// streaming: block = 64 m x 1024 d, 512 threads, 128 KB LDS.
// grid = (1024 m-steps, 1, 2 {keys,vals}).
// ---------------------------------------------------------------------------
__global__ __launch_bounds__(512)
void convert_tile(const float* __restrict__ keys,
                  const float* __restrict__ vals,
                  __hip_bfloat16* __restrict__ KtT,
                  __hip_bfloat16* __restrict__ VtT)
{
    __shared__ __align__(16) char Lt[1024 * 128];   // 128 KB

    const float* src = blockIdx.z ? vals : keys;
    char* dstb = (char*)(blockIdx.z ? VtT : KtT);

    const int tid = threadIdx.x;
    const int s   = blockIdx.x;          // m-step (64 m)
    const int m0  = s * 64;

    // ---- phase 1: full-row sequential reads, in-reg 4x4 transpose,
    //      granule-swizzled 8B LDS writes.
    const int dc = tid & 255;            // d-chunk (4 d), all 1024 d
    const int qh = tid >> 8;             // 0..1
    #pragma unroll
    for (int i = 0; i < 8; ++i) {
        const int q = 2 * i + qh;        // m-quad 0..15
        f32x4 v[4];
        #pragma unroll
        for (int r = 0; r < 4; ++r)
            v[r] = *(const f32x4*)(src + (size_t)(m0 + 4 * q + r) * D_DIM + 4 * dc);
        const int p8 = q ^ (dc & 15);    // phys granule = q ^ ((d>>2)&15)
        #pragma unroll
        for (int j = 0; j < 4; ++j) {
            bf16x4 w;
            #pragma unroll
            for (int r = 0; r < 4; ++r) w[r] = (__bf16)v[r][j];
            *(bf16x4*)(Lt + (4 * dc + j) * 128 + p8 * 8) = w;
        }
    }
    __syncthreads();

    // ---- phase 2: swizzle-resolving 8B reads, coalesced 16B global writes,
    //      emit all 8 d-tiles (output chunk-swizzle cl = c ^ (dl&7) baked in).
    #pragma unroll
    for (int ii = 0; ii < 16; ++ii) {
        const int idx = tid + ii * 512;      // 0..8191 16B-chunks
        const int t   = idx >> 10;           // d-tile 0..7
        const int dl  = (idx >> 3) & 127;    // row in tile
        const int c   = idx & 7;             // phys output chunk
        const int d   = t * 128 + dl;
        const int cl  = c ^ (dl & 7);        // logical chunk (8 m)
        const int h   = (dl >> 2) & 15;
        const int g0  = (2 * cl)     ^ h;
        const int g1  = (2 * cl + 1) ^ h;
        bf16x4 lo = *(const bf16x4*)(Lt + d * 128 + g0 * 8);
        bf16x4 hv = *(const bf16x4*)(Lt + d * 128 + g1 * 8);
        bf16x8 w;
        w[0] = lo[0]; w[1] = lo[1]; w[2] = lo[2]; w[3] = lo[3];
        w[4] = hv[0]; w[5] = hv[1]; w[6] = hv[2]; w[7] = hv[3];
        char* dst_tile = dstb + ((size_t)t * 1024 + s) * TILE_BYTES;
        *(bf16x8*)(dst_tile + dl * 128 + c * 16) = w;
    }
}

// ---------------------------------------------------------------------------
// Kernel A2: fp32 row-major [R][1024] -> tiles [r_tile][16][128][64], NO
// transpose.  Register-only, fully coalesced.  grid = (R/128, 16).
// ---------------------------------------------------------------------------
__global__ __launch_bounds__(256)
void convert_rows(const float* __restrict__ src,
                  __hip_bfloat16* __restrict__ dstT)
{
    const int tid = threadIdx.x;
    const int rt  = blockIdx.x;
    const int t   = blockIdx.y;
    const int r0  = rt * 128, d0 = t * 64;
    char* tile = (char*)dstT + ((size_t)rt * 16 + t) * TILE_BYTES;
    #pragma unroll
    for (int it = 0; it < 4; ++it) {
        const int idx = tid + it * 256;     // 0..1023
        const int r   = idx >> 3;           // 0..127
        const int cl  = idx & 7;            // logical chunk
        const float* p = src + (size_t)(r0 + r) * D_DIM + d0 + cl * 8;
        f32x4 a = *(const f32x4*)p;
        f32x4 b = *(const f32x4*)(p + 4);
        bf16x8 w;
        w[0] = (__bf16)a[0]; w[1] = (__bf16)a[1]; w[2] = (__bf16)a[2]; w[3] = (__bf16)a[3];
        w[4] = (__bf16)b[0]; w[5] = (__bf16)b[1]; w[6] = (__bf16)b[2]; w[7] = (__bf16)b[3];
        *(bf16x8*)(tile + r * 128 + ((cl ^ (r & 7)) * 16)) = w;
    }
}

// ---------------------------------------------------------------------------
// Kernel B: kvw[e][d] += sum_m V[e][m] * K[d][m].  8-phase 256x256
// (unchanged from R6-R11).
// ---------------------------------------------------------------------------
__global__ __launch_bounds__(512, 2)
void kv_gemm8(const __hip_bfloat16* __restrict__ VtT,
              const __hip_bfloat16* __restrict__ KtT,
              float* __restrict__ kvw)
{
    __shared__ __align__(16) char lds[2][4][TILE_BYTES];

    const int tid  = threadIdx.x;
    const int lane = tid & 63;
    const int wave = tid >> 6;
    const int we   = wave >> 2;
    const int wd   = wave & 3;

    const int bx    = blockIdx.x;
    const int xcd   = bx & 7;
    const int idx   = bx >> 3;
    const int chunk = ((idx >> 4) << 3) | xcd;
    const int t16   = idx & 15;
    const int E8    = t16 >> 2;
    const int D8    = t16 & 3;

    const size_t step0 = (size_t)chunk * 64;

    const char* Vb = (const char*)VtT;
    const char* Kb = (const char*)KtT;

    const int l15 = lane & 15;
    const int l7  = lane & 7;
    const int hi  = lane >> 4;

    f32x4 acc[8][4] = {};

    auto tileptr = [&](const char* base, int rt, int t) -> const char* {
        return base + ((size_t)rt * 1024 + step0 + (size_t)t) * TILE_BYTES;
    };
    auto stage_sub = [&](int buf, int sub, const char* tile) {
        char* dst = &lds[buf][sub][wave * 1024];
        const char* s = tile + wave * 1024 + lane * 16;
        gl_lds16(s,        dst);
        gl_lds16(s + 8192, dst + 8192);
    };

    stage_sub(0, 0, tileptr(Vb, 2 * E8,     0));
    stage_sub(0, 1, tileptr(Vb, 2 * E8 + 1, 0));
    stage_sub(0, 2, tileptr(Kb, 2 * D8,     0));
    stage_sub(0, 3, tileptr(Kb, 2 * D8 + 1, 0));
    asm volatile("s_waitcnt vmcnt(0)" ::: "memory");
    __builtin_amdgcn_s_barrier();

    bf16x8 bfr[4][2];

    #pragma unroll 2
    for (int t = 0; t < 64; ++t) {
        const int buf = t & 1;
        const char* abase = &lds[buf][we][0];
        const char* bbase = &lds[buf][2 + (wd >> 1)][0];
        const int brow0 = (wd & 1) * 64;

        #pragma unroll
        for (int p = 0; p < 4; ++p) {
            bf16x8 afr[2][2];
            #pragma unroll
            for (int j = 0; j < 2; ++j)
                #pragma unroll
                for (int ks = 0; ks < 2; ++ks) {
                    const int row = (2 * p + j) * 16 + l15;
                    afr[j][ks] = *(const bf16x8*)(abase + row * 128
                                   + (((ks << 2) + hi) ^ l7) * 16);
                }
            if (p == 0) {
                #pragma unroll
                for (int n = 0; n < 4; ++n)
                    #pragma unroll
                    for (int ks = 0; ks < 2; ++ks) {
                        const int row = brow0 + n * 16 + l15;
                        bfr[n][ks] = *(const bf16x8*)(bbase + row * 128
                                       + (((ks << 2) + hi) ^ l7) * 16);
                    }
            }
            if (p == 0 && t + 1 < 64) {
                stage_sub(buf ^ 1, 0, tileptr(Vb, 2 * E8,     t + 1));
                stage_sub(buf ^ 1, 1, tileptr(Vb, 2 * E8 + 1, t + 1));
            }
            if (p == 1 && t + 1 < 64) {
                stage_sub(buf ^ 1, 2, tileptr(Kb, 2 * D8,     t + 1));
                stage_sub(buf ^ 1, 3, tileptr(Kb, 2 * D8 + 1, t + 1));
            }
            __builtin_amdgcn_s_barrier();
            asm volatile("s_waitcnt lgkmcnt(0)" ::: "memory");
            __builtin_amdgcn_sched_barrier(0);
            __builtin_amdgcn_s_setprio(1);
            #pragma unroll
            for (int j = 0; j < 2; ++j)
                #pragma unroll
                for (int n = 0; n < 4; ++n)
                    #pragma unroll
                    for (int ks = 0; ks < 2; ++ks)
                        acc[2 * p + j][n] = mfma16(afr[j][ks], bfr[n][ks],
                                                   acc[2 * p + j][n]);
            __builtin_amdgcn_s_setprio(0);
            if (p == 3)
                asm volatile("s_waitcnt vmcnt(0)" ::: "memory");
            __builtin_amdgcn_s_barrier();
        }
    }

    const int rb = hi * 4;
    #pragma unroll
    for (int mi = 0; mi < 8; ++mi) {
        #pragma unroll
        for (int ni = 0; ni < 4; ++ni) {
            const int d = D8 * 256 + wd * 64 + ni * 16 + l15;
            #pragma unroll
            for (int r = 0; r < 4; ++r) {
                const int e = E8 * 256 + we * 128 + mi * 16 + rb + r;
                atomicAdd(kvw + (size_t)e * D_DIM + d, acc[mi][ni][r]);
            }
        }
    }
}

// ---------------------------------------------------------------------------
// Kernel C: out[r][e] = sum_d x[r][d] * kvw[e][d], both in tile format.
// 8-phase clone, 128(r) x 256(e) tile (unchanged from R9-R11).
// ---------------------------------------------------------------------------
__global__ __launch_bounds__(512, 1)
void out_gemm8(const __hip_bfloat16* __restrict__ xbT,
               const __hip_bfloat16* __restrict__ kvbT,
               float* __restrict__ out)
{
    __shared__ __align__(16) char lds[2][3][TILE_BYTES];   // 96 KB

    const int tid  = threadIdx.x;
    const int lane = tid & 63;
    const int wave = tid >> 6;
    const int wr   = wave >> 2;       // 0..1 r-half
    const int wee  = wave & 3;        // 0..3 e-quarter

    const int bx = blockIdx.x;
    const int rt = bx & 63;           // r-tile (128 rows)
    const int be = bx >> 6;           // 0..3 (256-col e-tile)

    const int l15 = lane & 15;
    const int l7  = lane & 7;
    const int hi  = lane >> 4;

    f32x4 acc[4][4] = {};

    const char* Xb = (const char*)xbT;
    const char* Kv = (const char*)kvbT;

    auto tileA = [&](int t) -> const char* {
        return Xb + ((size_t)rt * 16 + t) * TILE_BYTES;
    };
    auto tileB = [&](int j, int t) -> const char* {
        return Kv + ((size_t)(2 * be + j) * 16 + t) * TILE_BYTES;
    };
    auto stage_sub = [&](int buf, int sub, const char* tile) {
        char* dst = &lds[buf][sub][wave * 1024];
        const char* s = tile + wave * 1024 + lane * 16;
        gl_lds16(s,        dst);
        gl_lds16(s + 8192, dst + 8192);
    };

    stage_sub(0, 0, tileA(0));
    stage_sub(0, 1, tileB(0, 0));
    stage_sub(0, 2, tileB(1, 0));
    asm volatile("s_waitcnt vmcnt(0)" ::: "memory");
    __builtin_amdgcn_s_barrier();

    bf16x8 bfr[4][2];

    for (int t = 0; t < 16; ++t) {
        const int buf = t & 1;
        const char* abase = &lds[buf][0][0];
        const char* bbase = &lds[buf][1 + (wee >> 1)][0];
        const int brow0 = (wee & 1) * 64;

        #pragma unroll
        for (int p = 0; p < 4; ++p) {
            bf16x8 afr[2];
            #pragma unroll
            for (int ks = 0; ks < 2; ++ks) {
                const int row = wr * 64 + p * 16 + l15;
                afr[ks] = *(const bf16x8*)(abase + row * 128
                              + (((ks << 2) + hi) ^ l7) * 16);
            }
            if (p == 0) {
                #pragma unroll
                for (int n = 0; n < 4; ++n)
                    #pragma unroll
                    for (int ks = 0; ks < 2; ++ks) {
                        const int row = brow0 + n * 16 + l15;
                        bfr[n][ks] = *(const bf16x8*)(bbase + row * 128
                                       + (((ks << 2) + hi) ^ l7) * 16);
                    }
            }
            if (p == 0 && t + 1 < 16) stage_sub(buf ^ 1, 0, tileA(t + 1));
            if (p == 1 && t + 1 < 16) {
                stage_sub(buf ^ 1, 1, tileB(0, t + 1));
                stage_sub(buf ^ 1, 2, tileB(1, t + 1));
            }
            __builtin_amdgcn_s_barrier();
            asm volatile("s_waitcnt lgkmcnt(0)" ::: "memory");
            __builtin_amdgcn_sched_barrier(0);
            __builtin_amdgcn_s_setprio(1);
            #pragma unroll
            for (int n = 0; n < 4; ++n)
                #pragma unroll
                for (int ks = 0; ks < 2; ++ks)
                    acc[p][n] = mfma16(afr[ks], bfr[n][ks], acc[p][n]);
            __builtin_amdgcn_s_setprio(0);
            if (p == 3)
                asm volatile("s_waitcnt vmcnt(0)" ::: "memory");
            __builtin_amdgcn_s_barrier();
        }
    }

    // epilogue: C row = x rows = r; col = kvb rows = e  (m89 map)
    const int r0 = rt * 128, e0 = be * 256;
    #pragma unroll
    for (int mi = 0; mi < 4; ++mi) {
        #pragma unroll
        for (int ni = 0; ni < 4; ++ni) {
            const int e = e0 + wee * 64 + ni * 16 + l15;
            #pragma unroll
            for (int r = 0; r < 4; ++r) {
                const int rr = r0 + wr * 64 + mi * 16 + hi * 4 + r;
                out[(size_t)rr * D_DIM + e] = acc[mi][ni][r];
            }
        }
    }
}

// ---------------------------------------------------------------------------
// Fallbacks (ws too small): R1 fused kv path + old out path, known-correct.
// ---------------------------------------------------------------------------
__global__ __launch_bounds__(256)
void kv_partial_kernel(const float* __restrict__ keys,
                       const float* __restrict__ vals,
                       float* __restrict__ kvw)
{
    __shared__ __bf16 Ktl[BT][LDK];
    __shared__ __bf16 Vtl[BT][LDK];

    const int tid  = threadIdx.x;
    const int lane = tid & 63;
    const int wave = tid >> 6;
    const int wr   = wave >> 1;
    const int wc   = wave & 1;

    const int tile  = blockIdx.x & 63;
    const int chunk = blockIdx.x >> 6;
    const int d0 = (tile >> 3) * BT;
    const int e0 = (tile & 7) * BT;
    const size_t mbeg = (size_t)chunk * MC;

    f32x4 acc[4][4] = {};
    const int kg  = tid & 15;
    const int d4a = tid >> 4;

    for (int ms = 0; ms < MC; ms += BK) {
        #pragma unroll
        for (int i = 0; i < 2; ++i) {
            const int dloc = (d4a + i * 16) * 4;
            const size_t mrow = mbeg + ms + (size_t)kg * 4;
            f32x4 kr[4], vr[4];
            #pragma unroll
            for (int r = 0; r < 4; ++r) {
                kr[r] = *(const f32x4*)(keys + (mrow + r) * D_DIM + d0 + dloc);
                vr[r] = *(const f32x4*)(vals + (mrow + r) * D_DIM + e0 + dloc);
            }
            #pragma unroll
            for (int j = 0; j < 4; ++j) {
                bf16x4 wk, wv;
                #pragma unroll
                for (int r = 0; r < 4; ++r) {
                    wk[r] = (__bf16)kr[r][j];
                    wv[r] = (__bf16)vr[r][j];
                }
                *(bf16x4*)&Ktl[dloc + j][kg * 4] = wk;
                *(bf16x4*)&Vtl[dloc + j][kg * 4] = wv;
            }
        }
        __syncthreads();

        #pragma unroll
        for (int ks = 0; ks < BK; ks += 32) {
            bf16x8 af[4], bf[4];
            #pragma unroll
            for (int t = 0; t < 4; ++t) {
                af[t] = *(const bf16x8*)&Ktl[wr * 64 + t * 16 + (lane & 15)][ks + (lane >> 4) * 8];
                bf[t] = *(const bf16x8*)&Vtl[wc * 64 + t * 16 + (lane & 15)][ks + (lane >> 4) * 8];
            }
            #pragma unroll
            for (int mi = 0; mi < 4; ++mi)
                #pragma unroll
                for (int ni = 0; ni < 4; ++ni)
                    acc[mi][ni] = mfma16(af[mi], bf[ni], acc[mi][ni]);
        }
        __syncthreads();
    }

    const int rbase = (lane >> 4) * 4;
    const int cidx  = lane & 15;
    #pragma unroll
    for (int mi = 0; mi < 4; ++mi) {
        #pragma unroll
        for (int ni = 0; ni < 4; ++ni) {
            const int e = e0 + wc * 64 + ni * 16 + cidx;
            #pragma unroll
            for (int reg = 0; reg < 4; ++reg) {
                const int d = d0 + wr * 64 + mi * 16 + rbase + reg;
                atomicAdd(kvw + (size_t)e * D_DIM + d, acc[mi][ni][reg]);
            }
        }
    }
}

__global__ __launch_bounds__(256)
void out_gemm_kernel(const float* __restrict__ x,
                     const float* __restrict__ kvw,
                     float* __restrict__ out)
{
    __shared__ __bf16 Xt[BT][LDK];
    __shared__ __bf16 Wt[BT][LDK];

    const int tid  = threadIdx.x;
    const int lane = tid & 63;
    const int wave = tid >> 6;
    const int wr   = wave >> 1;
    const int wc   = wave & 1;

    const int r0 = blockIdx.x * BT;
    const int e0 = blockIdx.y * BT;

    f32x4 acc[4][4] = {};

    for (int ks0 = 0; ks0 < D_DIM; ks0 += BK) {
        #pragma unroll
        for (int i = 0; i < 8; ++i) {
            const int idx = tid + i * 256;
            const int row = idx >> 4;
            const int col = (idx & 15) * 4;
            f32x4 xa = *(const f32x4*)(x   + (size_t)(r0 + row) * D_DIM + ks0 + col);
            f32x4 wa = *(const f32x4*)(kvw + (size_t)(e0 + row) * D_DIM + ks0 + col);
            bf16x4 xb, wb;
            #pragma unroll
            for (int j = 0; j < 4; ++j) {
                xb[j] = (__bf16)xa[j];
                wb[j] = (__bf16)wa[j];
            }
            *(bf16x4*)&Xt[row][col] = xb;
            *(bf16x4*)&Wt[row][col] = wb;
        }
        __syncthreads();

        #pragma unroll
        for (int ks = 0; ks < BK; ks += 32) {
            bf16x8 af[4], bf[4];
            #pragma unroll
            for (int t = 0; t < 4; ++t) {
                af[t] = *(const bf16x8*)&Xt[wr * 64 + t * 16 + (lane & 15)][ks + (lane >> 4) * 8];
                bf[t] = *(const bf16x8*)&Wt[wc * 64 + t * 16 + (lane & 15)][ks + (lane >> 4) * 8];
            }
            #pragma unroll
            for (int mi = 0; mi < 4; ++mi)
                #pragma unroll
                for (int ni = 0; ni < 4; ++ni)
                    acc[mi][ni] = mfma16(af[mi], bf[ni], acc[mi][ni]);
        }
        __syncthreads();
    }

    const int rbase = (lane >> 4) * 4;
    const int cidx  = lane & 15;
    #pragma unroll
    for (int mi = 0; mi < 4; ++mi) {
        #pragma unroll
        for (int ni = 0; ni < 4; ++ni) {
            const int e = e0 + wc * 64 + ni * 16 + cidx;
            #pragma unroll
            for (int reg = 0; reg < 4; ++reg) {
                const int r = r0 + wr * 64 + mi * 16 + rbase + reg;
                out[(size_t)r * D_DIM + e] = acc[mi][ni][reg];
            }
        }
    }
}

extern "C" void kernel_launch(void* const* d_in, const int* in_sizes, int n_in,
                              void* d_out, int out_size, void* d_ws, size_t ws_size,
                              hipStream_t stream) {
    const float* x    = (const float*)d_in[0];
    const float* keys = (const float*)d_in[2];
    const float* vals = (const float*)d_in[3];
    float* out = (float*)d_out;

    const size_t kvw_bytes = (size_t)D_DIM * D_DIM * sizeof(float);          // 4 MiB
    const size_t kt_bytes  = (size_t)D_DIM * M_DIM * sizeof(__hip_bfloat16); // 128 MiB
    const size_t xb_bytes  = (size_t)ROWS * D_DIM * sizeof(__hip_bfloat16);  // 16 MiB
    const size_t kvb_bytes = (size_t)D_DIM * D_DIM * sizeof(__hip_bfloat16); // 2 MiB
    const size_t need_kv   = kvw_bytes + 2 * kt_bytes;
    const size_t need_full = need_kv + xb_bytes + kvb_bytes;

    float* kvw = (float*)d_ws;
    hipMemsetAsync(kvw, 0, kvw_bytes, stream);

    if (ws_size >= need_kv) {
        __hip_bfloat16* KtT = (__hip_bfloat16*)((char*)d_ws + kvw_bytes);
        __hip_bfloat16* VtT = (__hip_bfloat16*)((char*)d_ws + kvw_bytes + kt_bytes);
        convert_tile<<<dim3(M_DIM / 64, 1, 2), dim3(512), 0, stream>>>(
            keys, vals, KtT, VtT);
        kv_gemm8<<<dim3(256), dim3(512), 0, stream>>>(VtT, KtT, kvw);

        if (ws_size >= need_full) {
            __hip_bfloat16* xbT  = (__hip_bfloat16*)((char*)d_ws + need_kv);
            __hip_bfloat16* kvbT = (__hip_bfloat16*)((char*)d_ws + need_kv + xb_bytes);
            convert_rows<<<dim3(ROWS / 128, 16), dim3(256), 0, stream>>>(x, xbT);
            convert_rows<<<dim3(D_DIM / 128, 16), dim3(256), 0, stream>>>(kvw, kvbT);
            out_gemm8<<<dim3(256), dim3(512), 0, stream>>>(xbT, kvbT, out);
        } else {
            out_gemm_kernel<<<dim3(64, 8), dim3(256), 0, stream>>>(x, kvw, out);
        }
    } else {
        kv_partial_kernel<<<dim3(64 * NCHUNK), dim3(256), 0, stream>>>(keys, vals, kvw);
        out_gemm_kernel<<<dim3(64, 8), dim3(256), 0, stream>>>(x, kvw, out);
    }
}